// Round 16
// baseline (1314.374 us; speedup 1.0000x reference)
//
#include <hip/hip_runtime.h>
#include <hip/hip_bf16.h>

#define N_NODES 170000
#define N_EDGES 2400000
#define F_IN_   128
#define H_      64
#define C_OUT   40
#define L_LAYERS 8
#define LP1     9
#define EPS_T   1e-20f
#define ROW_ELEMS (LP1 * H_)   // 576 u16 per node row

typedef unsigned short u16;
typedef unsigned int u32;
typedef unsigned short u16x8 __attribute__((ext_vector_type(8)));
typedef short bf16x8 __attribute__((ext_vector_type(8)));
typedef float f32x4 __attribute__((ext_vector_type(4)));

__device__ __forceinline__ float bf2f(u16 u) {
    union { unsigned int i; float f; } c; c.i = ((unsigned int)u) << 16; return c.f;
}
__device__ __forceinline__ u16 f2bf(float f) {
    __hip_bfloat16 h = __float2bfloat16(f);           // RNE
    return *reinterpret_cast<u16*>(&h);
}

__device__ __forceinline__ float waveReduceSum(float v) {
    for (int m = 32; m; m >>= 1) v += __shfl_xor(v, m, 64);
    return v;
}

__global__ __launch_bounds__(256) void k_zero4(float4* __restrict__ p) {
    p[blockIdx.x * 256 + threadIdx.x] = make_float4(0.f, 0.f, 0.f, 0.f);
}

// ---------------- CSR build ----------------
// dst-range histogram: atomics confined to a 170KB deg window -> L2-resident
__global__ __launch_bounds__(256) void k_hist(
    const int* __restrict__ edst, int* __restrict__ deg, int lo, int hi)
{
    int e = blockIdx.x * 256 + threadIdx.x;
    if (e >= N_EDGES) return;
    int d = edst[e];
    if (d < lo || d >= hi) return;
    atomicAdd(&deg[d], 1);
}

#define SCAN_TPB 256
#define SCAN_VPT 8
#define SCAN_EPB (SCAN_TPB * SCAN_VPT)   // 2048
#define SCAN_BLOCKS ((N_NODES + SCAN_EPB - 1) / SCAN_EPB)  // 84

__global__ __launch_bounds__(SCAN_TPB) void k_scan1(
    const int* __restrict__ deg, int* __restrict__ rowstart,
    int* __restrict__ blockSums)
{
    __shared__ int tsum[SCAN_TPB];
    int tid = threadIdx.x;
    int base = blockIdx.x * SCAN_EPB + tid * SCAN_VPT;
    int vals[SCAN_VPT];
    int local = 0;
    #pragma unroll
    for (int i = 0; i < SCAN_VPT; ++i) {
        int idx = base + i;
        int v = (idx < N_NODES) ? deg[idx] : 0;
        vals[i] = local;
        local += v;
    }
    tsum[tid] = local;
    __syncthreads();
    for (int off = 1; off < SCAN_TPB; off <<= 1) {
        int v = (tid >= off) ? tsum[tid - off] : 0;
        __syncthreads();
        tsum[tid] += v;
        __syncthreads();
    }
    int texcl = tsum[tid] - local;
    #pragma unroll
    for (int i = 0; i < SCAN_VPT; ++i) {
        int idx = base + i;
        if (idx < N_NODES) rowstart[idx] = texcl + vals[i];
    }
    if (tid == SCAN_TPB - 1) blockSums[blockIdx.x] = tsum[tid];
}

__global__ __launch_bounds__(64) void k_scan2(int* __restrict__ blockSums) {
    if (threadIdx.x == 0) {
        int acc = 0;
        for (int i = 0; i < SCAN_BLOCKS; ++i) {
            int v = blockSums[i];
            blockSums[i] = acc;
            acc += v;
        }
    }
}

__global__ __launch_bounds__(SCAN_TPB) void k_scan3(
    int* __restrict__ rowstart, const int* __restrict__ blockSums)
{
    int off = blockSums[blockIdx.x];
    int base = blockIdx.x * SCAN_EPB + threadIdx.x * SCAN_VPT;
    #pragma unroll
    for (int i = 0; i < SCAN_VPT; ++i) {
        int idx = base + i;
        if (idx < N_NODES) rowstart[idx] += off;
    }
}

// dst-range pass: writes confined to a ~2.4 MB CSR window -> L2 write-combining
__global__ __launch_bounds__(256) void k_bucket(
    const int* __restrict__ esrc, const int* __restrict__ edst,
    const float* __restrict__ ew, const int* __restrict__ rowstart,
    int* __restrict__ cursor, int2* __restrict__ csr, int lo, int hi)
{
    int e = blockIdx.x * 256 + threadIdx.x;
    if (e >= N_EDGES) return;
    int d = edst[e];
    if (d < lo || d >= hi) return;
    int p = rowstart[d] + atomicAdd(&cursor[d], 1);
    csr[p] = make_int2(esrc[e], __float_as_int(ew[e]));
}

// ---------------- degree binning (wave load balance for k_prop) ----------------
// binsBuf layout (ints): [0..63] bins, [64..127] binStart, [128..191] binCursor
__global__ __launch_bounds__(256) void k_degbin(
    const int* __restrict__ deg, int* __restrict__ bins)
{
    __shared__ int h[64];
    int tid = threadIdx.x;
    if (tid < 64) h[tid] = 0;
    __syncthreads();
    for (int n = blockIdx.x * 256 + tid; n < N_NODES; n += gridDim.x * 256) {
        int d = deg[n]; if (d > 63) d = 63;
        atomicAdd(&h[d], 1);
    }
    __syncthreads();
    if (tid < 64 && h[tid] > 0) atomicAdd(&bins[tid], h[tid]);
}

__global__ __launch_bounds__(64) void k_degscan(int* __restrict__ binsBuf) {
    if (threadIdx.x == 0) {
        int acc = 0;
        for (int i = 0; i < 64; ++i) {
            binsBuf[64 + i] = acc;     // binStart
            acc += binsBuf[i];
        }
    }
}

__global__ __launch_bounds__(256) void k_degscatter(
    const int* __restrict__ deg, const int* __restrict__ rowstart,
    int* __restrict__ binsBuf, int* __restrict__ perm,
    int* __restrict__ rowstartP, int* __restrict__ degP)
{
    int n = blockIdx.x * 256 + threadIdx.x;
    if (n >= N_NODES) return;
    int d = deg[n];
    int db = (d > 63) ? 63 : d;
    int pos = binsBuf[64 + db] + atomicAdd(&binsBuf[128 + db], 1);
    perm[pos] = n;
    rowstartP[pos] = rowstart[n];
    degP[pos] = d;
}

// ---------------- node pipeline ----------------
// MFMA lin0: block = 256 nodes, 16x16x32 bf16 MFMA.
__global__ __launch_bounds__(256) void k_lin0(
    const float* __restrict__ x, const float* __restrict__ W0,
    const float* __restrict__ b0, u16* __restrict__ xMatB)
{
    __shared__ u16 Wt[H_ * F_IN_];   // 16 KB bf16: Wt[c*128 + (k ^ ((c&7)<<3))]
    int tid = threadIdx.x;
    for (int i = tid; i < F_IN_ * H_; i += 256) {
        int k = i >> 6, c = i & 63;              // W0[k][c] row-major
        Wt[c * F_IN_ + (k ^ ((c & 7) << 3))] = f2bf(W0[i]);
    }
    __syncthreads();

    int wave = tid >> 6, lane = tid & 63;
    int lg = lane >> 4;        // 0..3
    int lr = lane & 15;

    bf16x8 bfrag[4][4];
    float b0v[4];
    #pragma unroll
    for (int ct = 0; ct < 4; ++ct) {
        int c = ct * 16 + lr;
        #pragma unroll
        for (int kt = 0; kt < 4; ++kt) {
            int kidx = (kt * 32 + lg * 8) ^ ((c & 7) << 3);
            bfrag[ct][kt] = *reinterpret_cast<bf16x8*>(&Wt[c * F_IN_ + kidx]);
        }
        b0v[ct] = b0[c];
    }

    int nbase = blockIdx.x * 256 + wave * 64;
    #pragma unroll
    for (int m = 0; m < 4; ++m) {
        int arow = nbase + m * 16 + lr;
        int arowc = (arow < N_NODES) ? arow : (N_NODES - 1);
        const float4* xrow = (const float4*)(x + (size_t)arowc * F_IN_);
        f32x4 acc[4];
        #pragma unroll
        for (int ct = 0; ct < 4; ++ct) {
            acc[ct][0] = b0v[ct]; acc[ct][1] = b0v[ct];
            acc[ct][2] = b0v[ct]; acc[ct][3] = b0v[ct];
        }
        #pragma unroll
        for (int kt = 0; kt < 4; ++kt) {
            int k8 = kt * 8 + lg * 2;
            float4 xa = xrow[k8];
            float4 xb = xrow[k8 + 1];
            bf16x8 a;
            a[0] = (short)f2bf(xa.x); a[1] = (short)f2bf(xa.y);
            a[2] = (short)f2bf(xa.z); a[3] = (short)f2bf(xa.w);
            a[4] = (short)f2bf(xb.x); a[5] = (short)f2bf(xb.y);
            a[6] = (short)f2bf(xb.z); a[7] = (short)f2bf(xb.w);
            #pragma unroll
            for (int ct = 0; ct < 4; ++ct)
                acc[ct] = __builtin_amdgcn_mfma_f32_16x16x32_bf16(
                    a, bfrag[ct][kt], acc[ct], 0, 0, 0);
        }
        #pragma unroll
        for (int reg = 0; reg < 4; ++reg) {
            int n = nbase + m * 16 + lg * 4 + reg;
            if (n < N_NODES) {
                #pragma unroll
                for (int ct = 0; ct < 4; ++ct) {
                    float v = fmaxf(acc[ct][reg], 0.f);
                    xMatB[(size_t)n * ROW_ELEMS + ct * 16 + lr] = f2bf(v);
                }
            }
        }
    }
}

// 8 nodes per wave, 8 lanes/node (lane = 8 channels, ushort8); 2 gather chains.
// Degree-binned slot order: all 8 nodes in a wave have ~equal degree, so the
// while-loop trip count is ~mean instead of max-of-8 (r15's 4-chain regressed;
// this attacks the ~33% predicated-off slot waste instead).
__global__ __launch_bounds__(256) void k_prop(
    const u16* __restrict__ xMatB, int l,
    const int* __restrict__ perm, const int* __restrict__ rowstartP,
    const int* __restrict__ degP,
    const int2* __restrict__ csr, u16* __restrict__ xMatOut)
{
    int tid = threadIdx.x;
    int oc = tid & 7;
    int slot = blockIdx.x * 32 + (tid >> 3);
    bool valid = (slot < N_NODES);
    int n     = valid ? perm[slot]      : 0;
    int start = valid ? rowstartP[slot] : 0;
    int d     = valid ? degP[slot]      : 0;

    const unsigned loff = (unsigned)l * H_ + oc * 8;
    float acc0[8] = {0.f,0.f,0.f,0.f,0.f,0.f,0.f,0.f};
    float acc1[8] = {0.f,0.f,0.f,0.f,0.f,0.f,0.f,0.f};

    int t = 0;
    while (__any(t < d)) {
        if (t < d) {
            int2 e = csr[start + t];
            float w = __int_as_float(e.y);
            u16x8 v = *reinterpret_cast<const u16x8*>(
                &xMatB[(size_t)(unsigned)e.x * ROW_ELEMS + loff]);
            #pragma unroll
            for (int j = 0; j < 8; ++j) acc0[j] = fmaf(bf2f(v[j]), w, acc0[j]);
        }
        if (t + 1 < d) {
            int2 e = csr[start + t + 1];
            float w = __int_as_float(e.y);
            u16x8 v = *reinterpret_cast<const u16x8*>(
                &xMatB[(size_t)(unsigned)e.x * ROW_ELEMS + loff]);
            #pragma unroll
            for (int j = 0; j < 8; ++j) acc1[j] = fmaf(bf2f(v[j]), w, acc1[j]);
        }
        t += 2;
    }

    if (valid) {
        u16x8 o;
        #pragma unroll
        for (int j = 0; j < 8; ++j) o[j] = f2bf(fmaxf(acc0[j] + acc1[j], 0.f));
        __builtin_nontemporal_store(o, reinterpret_cast<u16x8*>(
            &xMatOut[(size_t)n * ROW_ELEMS + (l + 1) * H_ + oc * 8]));
    }
}

// fused gate+mix: 8 lanes/node (unchanged)
__global__ __launch_bounds__(256) void k_gatemix(
    const u16* __restrict__ xMatB, const float* __restrict__ gum,
    const float* __restrict__ mw, const float* __restrict__ mb,
    u16* __restrict__ mix, float* __restrict__ entPart)
{
    __shared__ float lds[4];
    int tid = threadIdx.x;
    int oc = tid & 7;
    int n = blockIdx.x * 32 + (tid >> 3);
    bool valid = (n < N_NODES);
    int nc = valid ? n : (N_NODES - 1);
    const u16* row = &xMatB[(size_t)nc * ROW_ELEMS + oc * 8];

    float mwv[8];
    #pragma unroll
    for (int q = 0; q < 8; ++q) mwv[q] = mw[oc * 8 + q];
    float mb0 = mb[0];

    u16x8 v[LP1];
    float r[LP1];
    #pragma unroll
    for (int j = 0; j < LP1; ++j) {
        v[j] = *reinterpret_cast<const u16x8*>(&row[j * H_]);
        float dot = 0.f;
        #pragma unroll
        for (int q = 0; q < 8; ++q) dot = fmaf(bf2f(v[j][q]), mwv[q], dot);
        dot += __shfl_xor(dot, 1, 64);
        dot += __shfl_xor(dot, 2, 64);
        dot += __shfl_xor(dot, 4, 64);
        r[j] = dot + mb0;
    }
    float gmine = valid ? gum[(size_t)n * LP1 + oc] : 0.f;
    float g8    = (valid && oc == 0) ? gum[(size_t)n * LP1 + 8] : 0.f;
    int gbase = tid & 56;

    float t[LP1], lg[LP1];
    float cp = 1.f;
    #pragma unroll
    for (int j = 0; j < LP1; ++j) {
        float s = 1.f / (1.f + expf(-r[j]));
        t[j] = (j == L_LAYERS) ? cp : s * cp;
        cp *= (1.f - s);
    }
    float ent = 0.f, mx = -INFINITY;
    #pragma unroll
    for (int j = 0; j < LP1; ++j) {
        float lt = logf(t[j] + EPS_T);
        ent -= t[j] * lt;
        float g = (j < 8) ? __shfl(gmine, (gbase & 56) + j, 64)
                          : __shfl(g8, gbase & 56, 64);
        lg[j] = lt + g;
        mx = fmaxf(mx, lg[j]);
    }
    float se = 0.f;
    #pragma unroll
    for (int j = 0; j < LP1; ++j) { lg[j] = expf(lg[j] - mx); se += lg[j]; }
    float inv = 1.f / se;

    float acc[8] = {0.f,0.f,0.f,0.f,0.f,0.f,0.f,0.f};
    #pragma unroll
    for (int j = 0; j < LP1; ++j) {
        float w = lg[j] * inv;
        #pragma unroll
        for (int q = 0; q < 8; ++q) acc[q] = fmaf(bf2f(v[j][q]), w, acc[q]);
    }
    if (valid) {
        u16x8 o;
        #pragma unroll
        for (int q = 0; q < 8; ++q) o[q] = f2bf(acc[q]);
        *reinterpret_cast<u16x8*>(&mix[(size_t)n * H_ + oc * 8]) = o;
    }

    float e = (valid && oc == 0) ? ent : 0.f;
    e = waveReduceSum(e);
    int wave = tid >> 6, lane = tid & 63;
    if (lane == 0) lds[wave] = e;
    __syncthreads();
    if (tid == 0) entPart[blockIdx.x] = lds[0] + lds[1] + lds[2] + lds[3];
}

// MFMA lin1 + log_softmax: out[N,40] = mix[N,64] @ W1[64,40] + b1
__global__ __launch_bounds__(256) void k_lin1(
    const u16* __restrict__ mix, const float* __restrict__ W1,
    const float* __restrict__ b1, float* __restrict__ out)
{
    __shared__ u16 Wl[48 * 64];   // 6 KB: Wl[c*64 + (k ^ ((c&7)<<3))], c>=40 -> 0
    int tid = threadIdx.x;
    for (int i = tid; i < 48 * 64; i += 256) {
        int c = i >> 6, k = i & 63;
        float v = (c < C_OUT) ? W1[k * C_OUT + c] : 0.f;
        Wl[c * 64 + (k ^ ((c & 7) << 3))] = f2bf(v);
    }
    __syncthreads();

    int wave = tid >> 6, lane = tid & 63;
    int lg = lane >> 4, lr = lane & 15;

    bf16x8 bfrag[3][2];
    float b1v[3];
    #pragma unroll
    for (int ct = 0; ct < 3; ++ct) {
        int c = ct * 16 + lr;
        #pragma unroll
        for (int kt = 0; kt < 2; ++kt) {
            int kidx = (kt * 32 + lg * 8) ^ ((c & 7) << 3);
            bfrag[ct][kt] = *reinterpret_cast<bf16x8*>(&Wl[c * 64 + kidx]);
        }
        b1v[ct] = (c < C_OUT) ? b1[c] : 0.f;
    }

    int nbase = blockIdx.x * 64 + wave * 16;
    int arow = nbase + lr;
    int arowc = (arow < N_NODES) ? arow : (N_NODES - 1);
    const u16* mrow = &mix[(size_t)arowc * H_];

    f32x4 acc[3];
    #pragma unroll
    for (int ct = 0; ct < 3; ++ct) {
        acc[ct][0] = b1v[ct]; acc[ct][1] = b1v[ct];
        acc[ct][2] = b1v[ct]; acc[ct][3] = b1v[ct];
    }
    #pragma unroll
    for (int kt = 0; kt < 2; ++kt) {
        bf16x8 a = *reinterpret_cast<const bf16x8*>(&mrow[kt * 32 + lg * 8]);
        #pragma unroll
        for (int ct = 0; ct < 3; ++ct)
            acc[ct] = __builtin_amdgcn_mfma_f32_16x16x32_bf16(
                a, bfrag[ct][kt], acc[ct], 0, 0, 0);
    }
    #pragma unroll
    for (int reg = 0; reg < 4; ++reg) {
        float v0 = acc[0][reg], v1 = acc[1][reg];
        float v2 = (lr < 8) ? acc[2][reg] : -INFINITY;
        float mx = fmaxf(fmaxf(v0, v1), v2);
        mx = fmaxf(mx, __shfl_xor(mx, 1, 64));
        mx = fmaxf(mx, __shfl_xor(mx, 2, 64));
        mx = fmaxf(mx, __shfl_xor(mx, 4, 64));
        mx = fmaxf(mx, __shfl_xor(mx, 8, 64));
        float e = expf(v0 - mx) + expf(v1 - mx) + ((lr < 8) ? expf(v2 - mx) : 0.f);
        e += __shfl_xor(e, 1, 64);
        e += __shfl_xor(e, 2, 64);
        e += __shfl_xor(e, 4, 64);
        e += __shfl_xor(e, 8, 64);
        float ls = mx + logf(e);
        int n = nbase + lg * 4 + reg;
        if (n < N_NODES) {
            out[(size_t)n * C_OUT + lr]      = v0 - ls;
            out[(size_t)n * C_OUT + 16 + lr] = v1 - ls;
            if (lr < 8) out[(size_t)n * C_OUT + 32 + lr] = v2 - ls;
        }
    }
}

__global__ __launch_bounds__(256) void k_entreduce(
    const float* __restrict__ part, int n, float scale, float* __restrict__ out)
{
    __shared__ float lds[4];
    int tid = threadIdx.x;
    float s = 0.f;
    for (int i = tid; i < n; i += 256) s += part[i];
    s = waveReduceSum(s);
    int wave = tid >> 6, lane = tid & 63;
    if (lane == 0) lds[wave] = s;
    __syncthreads();
    if (tid == 0) out[0] = (lds[0] + lds[1] + lds[2] + lds[3]) * scale;
}

extern "C" void kernel_launch(void* const* d_in, const int* in_sizes, int n_in,
                              void* d_out, int out_size, void* d_ws, size_t ws_size,
                              hipStream_t stream)
{
    const float* x   = (const float*)d_in[0];
    const float* ew  = (const float*)d_in[1];
    const float* gum = (const float*)d_in[2];
    const float* W0  = (const float*)d_in[3];
    const float* b0  = (const float*)d_in[4];
    const float* mw  = (const float*)d_in[5];
    const float* mb  = (const float*)d_in[6];
    const float* W1  = (const float*)d_in[7];
    const float* b1  = (const float*)d_in[8];
    const int* esrc  = (const int*)d_in[9];
    const int* edst  = (const int*)d_in[10];
    float* out = (float*)d_out;

    const int propBlocks = (N_NODES + 31) / 32;         // 5313

    const size_t xMatBytes = (size_t)N_NODES * ROW_ELEMS * sizeof(u16); // 195,840,000
    const size_t degBytes  = (size_t)N_NODES * sizeof(int);
    const size_t curBytes  = (size_t)N_NODES * sizeof(int);
    const size_t rowBytes  = (size_t)N_NODES * sizeof(int);
    const size_t bsBytes   = 512;
    const size_t csrBytes  = (size_t)N_EDGES * sizeof(int2);            //  19,200,000
    const size_t mixBytes  = (size_t)N_NODES * H_ * sizeof(u16);        //  21,760,000
    const size_t entBytes  = (size_t)propBlocks * sizeof(float);        //      21,252
    const size_t permBytes = (size_t)N_NODES * sizeof(int);             //     680,000
    const size_t binsBytes = 4096;
    const size_t need = xMatBytes + degBytes + curBytes + rowBytes + bsBytes +
                        csrBytes + mixBytes + entBytes + 3 * permBytes +
                        binsBytes;                                      // ~241 MB
    if (ws_size < need) return;

    char* p = (char*)d_ws;
    u16*  xMatB    = (u16*)p;           p += xMatBytes;
    int*  deg      = (int*)p;           p += degBytes;
    int*  cursor   = (int*)p;           p += curBytes;   // deg+cursor zeroed together
    int*  rowstart = (int*)p;           p += rowBytes;
    int*  blockSums= (int*)p;           p += bsBytes;
    int2* csr      = (int2*)p;          p += csrBytes;
    u16*  mixbuf   = (u16*)p;           p += mixBytes;
    float* entP    = (float*)p;         p += entBytes;
    int*  perm     = (int*)p;           p += permBytes;
    int*  rowstartP= (int*)p;           p += permBytes;
    int*  degP     = (int*)p;           p += permBytes;
    int*  binsBuf  = (int*)p;           // 4KB: [0..63] bins, [64..127] start, [128..191] cursor

    const int edgeBlocks = (N_EDGES + 255) / 256;       // 9375
    const int lin0Blocks = (N_NODES + 255) / 256;       // 665
    const int gmixBlocks = propBlocks;                  // 5313
    const int lin1Blocks = (N_NODES + 63) / 64;         // 2657
    const int nodeBlocks = (N_NODES + 255) / 256;       // 665

    // CSR build (k_zero4 zeroes deg+cursor; 3968B tail spills into rowstart,
    // which scan rewrites fully before any read)
    k_zero4<<<333, 256, 0, stream>>>((float4*)deg);
    k_zero4<<<1, 256, 0, stream>>>((float4*)binsBuf);
    const int STEP_H = N_NODES / 4;                     // 42500: 170KB deg window
    for (int i = 0; i < 4; ++i)
        k_hist<<<edgeBlocks, 256, 0, stream>>>(edst, deg, i * STEP_H,
                                               (i + 1) * STEP_H);
    k_scan1<<<SCAN_BLOCKS, SCAN_TPB, 0, stream>>>(deg, rowstart, blockSums);
    k_scan2<<<1, 64, 0, stream>>>(blockSums);
    k_scan3<<<SCAN_BLOCKS, SCAN_TPB, 0, stream>>>(rowstart, blockSums);
    const int STEP_B = N_NODES / 8;                     // 21250: 2.4MB csr window
    for (int i = 0; i < 8; ++i)
        k_bucket<<<edgeBlocks, 256, 0, stream>>>(esrc, edst, ew, rowstart,
                                                 cursor, csr, i * STEP_B,
                                                 (i + 1) * STEP_B);

    // degree binning (perm + gathered rowstart/deg for balanced prop waves)
    k_degbin<<<256, 256, 0, stream>>>(deg, binsBuf);
    k_degscan<<<1, 64, 0, stream>>>(binsBuf);
    k_degscatter<<<nodeBlocks, 256, 0, stream>>>(deg, rowstart, binsBuf,
                                                 perm, rowstartP, degP);

    // node pipeline
    k_lin0<<<lin0Blocks, 256, 0, stream>>>(x, W0, b0, xMatB);
    for (int l = 0; l < L_LAYERS; ++l)
        k_prop<<<propBlocks, 256, 0, stream>>>(xMatB, l, perm, rowstartP, degP,
                                               csr, xMatB);
    k_gatemix<<<gmixBlocks, 256, 0, stream>>>(xMatB, gum, mw, mb, mixbuf, entP);
    k_lin1<<<lin1Blocks, 256, 0, stream>>>(mixbuf, W1, b1, out);
    k_entreduce<<<1, 256, 0, stream>>>(entP, gmixBlocks, 1.0f / N_NODES,
                                       out + (size_t)N_NODES * C_OUT);
}

// Round 17
// 828.174 us; speedup vs baseline: 1.5871x; 1.5871x over previous
//
#include <hip/hip_runtime.h>
#include <hip/hip_bf16.h>

#define N_NODES 170000
#define N_EDGES 2400000
#define F_IN_   128
#define H_      64
#define C_OUT   40
#define L_LAYERS 8
#define LP1     9
#define EPS_T   1e-20f
#define ROW_ELEMS (LP1 * H_)   // 576 u16 per node row

typedef unsigned short u16;
typedef unsigned short u16x8 __attribute__((ext_vector_type(8)));
typedef short bf16x8 __attribute__((ext_vector_type(8)));
typedef float f32x4 __attribute__((ext_vector_type(4)));

__device__ __forceinline__ float bf2f(u16 u) {
    union { unsigned int i; float f; } c; c.i = ((unsigned int)u) << 16; return c.f;
}
__device__ __forceinline__ u16 f2bf(float f) {
    __hip_bfloat16 h = __float2bfloat16(f);           // RNE
    return *reinterpret_cast<u16*>(&h);
}

__device__ __forceinline__ float waveReduceSum(float v) {
    for (int m = 32; m; m >>= 1) v += __shfl_xor(v, m, 64);
    return v;
}

__global__ __launch_bounds__(256) void k_zero4(float4* __restrict__ p) {
    p[blockIdx.x * 256 + threadIdx.x] = make_float4(0.f, 0.f, 0.f, 0.f);
}

// ---------------- CSR build ----------------
// dst-range histogram: atomics confined to a 340KB deg window -> L2-resident
__global__ __launch_bounds__(256) void k_hist(
    const int* __restrict__ edst, int* __restrict__ deg, int lo, int hi)
{
    int e = blockIdx.x * 256 + threadIdx.x;
    if (e >= N_EDGES) return;
    int d = edst[e];
    if (d < lo || d >= hi) return;
    atomicAdd(&deg[d], 1);
}

#define SCAN_TPB 256
#define SCAN_VPT 8
#define SCAN_EPB (SCAN_TPB * SCAN_VPT)   // 2048
#define SCAN_BLOCKS ((N_NODES + SCAN_EPB - 1) / SCAN_EPB)  // 84

__global__ __launch_bounds__(SCAN_TPB) void k_scan1(
    const int* __restrict__ deg, int* __restrict__ rowstart,
    int* __restrict__ blockSums)
{
    __shared__ int tsum[SCAN_TPB];
    int tid = threadIdx.x;
    int base = blockIdx.x * SCAN_EPB + tid * SCAN_VPT;
    int vals[SCAN_VPT];
    int local = 0;
    #pragma unroll
    for (int i = 0; i < SCAN_VPT; ++i) {
        int idx = base + i;
        int v = (idx < N_NODES) ? deg[idx] : 0;
        vals[i] = local;
        local += v;
    }
    tsum[tid] = local;
    __syncthreads();
    for (int off = 1; off < SCAN_TPB; off <<= 1) {
        int v = (tid >= off) ? tsum[tid - off] : 0;
        __syncthreads();
        tsum[tid] += v;
        __syncthreads();
    }
    int texcl = tsum[tid] - local;
    #pragma unroll
    for (int i = 0; i < SCAN_VPT; ++i) {
        int idx = base + i;
        if (idx < N_NODES) rowstart[idx] = texcl + vals[i];
    }
    if (tid == SCAN_TPB - 1) blockSums[blockIdx.x] = tsum[tid];
}

__global__ __launch_bounds__(64) void k_scan2(int* __restrict__ blockSums) {
    if (threadIdx.x == 0) {
        int acc = 0;
        for (int i = 0; i < SCAN_BLOCKS; ++i) {
            int v = blockSums[i];
            blockSums[i] = acc;
            acc += v;
        }
    }
}

__global__ __launch_bounds__(SCAN_TPB) void k_scan3(
    int* __restrict__ rowstart, const int* __restrict__ blockSums)
{
    int off = blockSums[blockIdx.x];
    int base = blockIdx.x * SCAN_EPB + threadIdx.x * SCAN_VPT;
    #pragma unroll
    for (int i = 0; i < SCAN_VPT; ++i) {
        int idx = base + i;
        if (idx < N_NODES) rowstart[idx] += off;
    }
}

// dst-range pass: writes confined to a ~2.4 MB CSR window -> L2 write-combining
__global__ __launch_bounds__(256) void k_bucket(
    const int* __restrict__ esrc, const int* __restrict__ edst,
    const float* __restrict__ ew, const int* __restrict__ rowstart,
    int* __restrict__ cursor, int2* __restrict__ csr, int lo, int hi)
{
    int e = blockIdx.x * 256 + threadIdx.x;
    if (e >= N_EDGES) return;
    int d = edst[e];
    if (d < lo || d >= hi) return;
    int p = rowstart[d] + atomicAdd(&cursor[d], 1);
    csr[p] = make_int2(esrc[e], __float_as_int(ew[e]));
}

// ---------------- node pipeline ----------------
// MFMA lin0: block = 256 nodes, 16x16x32 bf16 MFMA.
__global__ __launch_bounds__(256) void k_lin0(
    const float* __restrict__ x, const float* __restrict__ W0,
    const float* __restrict__ b0, u16* __restrict__ xMatB)
{
    __shared__ u16 Wt[H_ * F_IN_];   // 16 KB bf16: Wt[c*128 + (k ^ ((c&7)<<3))]
    int tid = threadIdx.x;
    for (int i = tid; i < F_IN_ * H_; i += 256) {
        int k = i >> 6, c = i & 63;              // W0[k][c] row-major
        Wt[c * F_IN_ + (k ^ ((c & 7) << 3))] = f2bf(W0[i]);
    }
    __syncthreads();

    int wave = tid >> 6, lane = tid & 63;
    int lg = lane >> 4;        // 0..3
    int lr = lane & 15;

    bf16x8 bfrag[4][4];
    float b0v[4];
    #pragma unroll
    for (int ct = 0; ct < 4; ++ct) {
        int c = ct * 16 + lr;
        #pragma unroll
        for (int kt = 0; kt < 4; ++kt) {
            int kidx = (kt * 32 + lg * 8) ^ ((c & 7) << 3);
            bfrag[ct][kt] = *reinterpret_cast<bf16x8*>(&Wt[c * F_IN_ + kidx]);
        }
        b0v[ct] = b0[c];
    }

    int nbase = blockIdx.x * 256 + wave * 64;
    #pragma unroll
    for (int m = 0; m < 4; ++m) {
        int arow = nbase + m * 16 + lr;
        int arowc = (arow < N_NODES) ? arow : (N_NODES - 1);
        const float4* xrow = (const float4*)(x + (size_t)arowc * F_IN_);
        f32x4 acc[4];
        #pragma unroll
        for (int ct = 0; ct < 4; ++ct) {
            acc[ct][0] = b0v[ct]; acc[ct][1] = b0v[ct];
            acc[ct][2] = b0v[ct]; acc[ct][3] = b0v[ct];
        }
        #pragma unroll
        for (int kt = 0; kt < 4; ++kt) {
            int k8 = kt * 8 + lg * 2;
            float4 xa = xrow[k8];
            float4 xb = xrow[k8 + 1];
            bf16x8 a;
            a[0] = (short)f2bf(xa.x); a[1] = (short)f2bf(xa.y);
            a[2] = (short)f2bf(xa.z); a[3] = (short)f2bf(xa.w);
            a[4] = (short)f2bf(xb.x); a[5] = (short)f2bf(xb.y);
            a[6] = (short)f2bf(xb.z); a[7] = (short)f2bf(xb.w);
            #pragma unroll
            for (int ct = 0; ct < 4; ++ct)
                acc[ct] = __builtin_amdgcn_mfma_f32_16x16x32_bf16(
                    a, bfrag[ct][kt], acc[ct], 0, 0, 0);
        }
        #pragma unroll
        for (int reg = 0; reg < 4; ++reg) {
            int n = nbase + m * 16 + lg * 4 + reg;
            if (n < N_NODES) {
                #pragma unroll
                for (int ct = 0; ct < 4; ++ct) {
                    float v = fmaxf(acc[ct][reg], 0.f);
                    xMatB[(size_t)n * ROW_ELEMS + ct * 16 + lr] = f2bf(v);
                }
            }
        }
    }
}

// 8 nodes per wave, 8 lanes/node (lane = 8 channels, ushort8); 2 gather chains.
// (r15's 4 chains and r16's degree binning both failed to beat this — the
// random-line fabric path is the limit at ~2.5 TB/s of L2-miss traffic.)
__global__ __launch_bounds__(256) void k_prop(
    const u16* __restrict__ xMatB, int l,
    const int* __restrict__ rowstart, const int* __restrict__ deg,
    const int2* __restrict__ csr, u16* __restrict__ xMatOut)
{
    int tid = threadIdx.x;
    int oc = tid & 7;
    int n = blockIdx.x * 32 + (tid >> 3);
    bool valid = (n < N_NODES);
    int start = valid ? rowstart[n] : 0;
    int d     = valid ? deg[n]      : 0;

    const unsigned loff = (unsigned)l * H_ + oc * 8;
    float acc0[8] = {0.f,0.f,0.f,0.f,0.f,0.f,0.f,0.f};
    float acc1[8] = {0.f,0.f,0.f,0.f,0.f,0.f,0.f,0.f};

    int t = 0;
    while (__any(t < d)) {
        if (t < d) {
            int2 e = csr[start + t];
            float w = __int_as_float(e.y);
            u16x8 v = *reinterpret_cast<const u16x8*>(
                &xMatB[(size_t)(unsigned)e.x * ROW_ELEMS + loff]);
            #pragma unroll
            for (int j = 0; j < 8; ++j) acc0[j] = fmaf(bf2f(v[j]), w, acc0[j]);
        }
        if (t + 1 < d) {
            int2 e = csr[start + t + 1];
            float w = __int_as_float(e.y);
            u16x8 v = *reinterpret_cast<const u16x8*>(
                &xMatB[(size_t)(unsigned)e.x * ROW_ELEMS + loff]);
            #pragma unroll
            for (int j = 0; j < 8; ++j) acc1[j] = fmaf(bf2f(v[j]), w, acc1[j]);
        }
        t += 2;
    }

    if (valid) {
        u16x8 o;
        #pragma unroll
        for (int j = 0; j < 8; ++j) o[j] = f2bf(fmaxf(acc0[j] + acc1[j], 0.f));
        __builtin_nontemporal_store(o, reinterpret_cast<u16x8*>(
            &xMatOut[(size_t)n * ROW_ELEMS + (l + 1) * H_ + oc * 8]));
    }
}

// fused gate+mix: 8 lanes/node
__global__ __launch_bounds__(256) void k_gatemix(
    const u16* __restrict__ xMatB, const float* __restrict__ gum,
    const float* __restrict__ mw, const float* __restrict__ mb,
    u16* __restrict__ mix, float* __restrict__ entPart)
{
    __shared__ float lds[4];
    int tid = threadIdx.x;
    int oc = tid & 7;
    int n = blockIdx.x * 32 + (tid >> 3);
    bool valid = (n < N_NODES);
    int nc = valid ? n : (N_NODES - 1);
    const u16* row = &xMatB[(size_t)nc * ROW_ELEMS + oc * 8];

    float mwv[8];
    #pragma unroll
    for (int q = 0; q < 8; ++q) mwv[q] = mw[oc * 8 + q];
    float mb0 = mb[0];

    u16x8 v[LP1];
    float r[LP1];
    #pragma unroll
    for (int j = 0; j < LP1; ++j) {
        v[j] = *reinterpret_cast<const u16x8*>(&row[j * H_]);
        float dot = 0.f;
        #pragma unroll
        for (int q = 0; q < 8; ++q) dot = fmaf(bf2f(v[j][q]), mwv[q], dot);
        dot += __shfl_xor(dot, 1, 64);
        dot += __shfl_xor(dot, 2, 64);
        dot += __shfl_xor(dot, 4, 64);
        r[j] = dot + mb0;
    }
    float gmine = valid ? gum[(size_t)n * LP1 + oc] : 0.f;
    float g8    = (valid && oc == 0) ? gum[(size_t)n * LP1 + 8] : 0.f;
    int gbase = tid & 56;

    float t[LP1], lg[LP1];
    float cp = 1.f;
    #pragma unroll
    for (int j = 0; j < LP1; ++j) {
        float s = 1.f / (1.f + expf(-r[j]));
        t[j] = (j == L_LAYERS) ? cp : s * cp;
        cp *= (1.f - s);
    }
    float ent = 0.f, mx = -INFINITY;
    #pragma unroll
    for (int j = 0; j < LP1; ++j) {
        float lt = logf(t[j] + EPS_T);
        ent -= t[j] * lt;
        float g = (j < 8) ? __shfl(gmine, (gbase & 56) + j, 64)
                          : __shfl(g8, gbase & 56, 64);
        lg[j] = lt + g;
        mx = fmaxf(mx, lg[j]);
    }
    float se = 0.f;
    #pragma unroll
    for (int j = 0; j < LP1; ++j) { lg[j] = expf(lg[j] - mx); se += lg[j]; }
    float inv = 1.f / se;

    float acc[8] = {0.f,0.f,0.f,0.f,0.f,0.f,0.f,0.f};
    #pragma unroll
    for (int j = 0; j < LP1; ++j) {
        float w = lg[j] * inv;
        #pragma unroll
        for (int q = 0; q < 8; ++q) acc[q] = fmaf(bf2f(v[j][q]), w, acc[q]);
    }
    if (valid) {
        u16x8 o;
        #pragma unroll
        for (int q = 0; q < 8; ++q) o[q] = f2bf(acc[q]);
        *reinterpret_cast<u16x8*>(&mix[(size_t)n * H_ + oc * 8]) = o;
    }

    float e = (valid && oc == 0) ? ent : 0.f;
    e = waveReduceSum(e);
    int wave = tid >> 6, lane = tid & 63;
    if (lane == 0) lds[wave] = e;
    __syncthreads();
    if (tid == 0) entPart[blockIdx.x] = lds[0] + lds[1] + lds[2] + lds[3];
}

// MFMA lin1 + log_softmax: out[N,40] = mix[N,64] @ W1[64,40] + b1
__global__ __launch_bounds__(256) void k_lin1(
    const u16* __restrict__ mix, const float* __restrict__ W1,
    const float* __restrict__ b1, float* __restrict__ out)
{
    __shared__ u16 Wl[48 * 64];   // 6 KB: Wl[c*64 + (k ^ ((c&7)<<3))], c>=40 -> 0
    int tid = threadIdx.x;
    for (int i = tid; i < 48 * 64; i += 256) {
        int c = i >> 6, k = i & 63;
        float v = (c < C_OUT) ? W1[k * C_OUT + c] : 0.f;
        Wl[c * 64 + (k ^ ((c & 7) << 3))] = f2bf(v);
    }
    __syncthreads();

    int wave = tid >> 6, lane = tid & 63;
    int lg = lane >> 4, lr = lane & 15;

    bf16x8 bfrag[3][2];
    float b1v[3];
    #pragma unroll
    for (int ct = 0; ct < 3; ++ct) {
        int c = ct * 16 + lr;
        #pragma unroll
        for (int kt = 0; kt < 2; ++kt) {
            int kidx = (kt * 32 + lg * 8) ^ ((c & 7) << 3);
            bfrag[ct][kt] = *reinterpret_cast<bf16x8*>(&Wl[c * 64 + kidx]);
        }
        b1v[ct] = (c < C_OUT) ? b1[c] : 0.f;
    }

    int nbase = blockIdx.x * 64 + wave * 16;
    int arow = nbase + lr;
    int arowc = (arow < N_NODES) ? arow : (N_NODES - 1);
    const u16* mrow = &mix[(size_t)arowc * H_];

    f32x4 acc[3];
    #pragma unroll
    for (int ct = 0; ct < 3; ++ct) {
        acc[ct][0] = b1v[ct]; acc[ct][1] = b1v[ct];
        acc[ct][2] = b1v[ct]; acc[ct][3] = b1v[ct];
    }
    #pragma unroll
    for (int kt = 0; kt < 2; ++kt) {
        bf16x8 a = *reinterpret_cast<const bf16x8*>(&mrow[kt * 32 + lg * 8]);
        #pragma unroll
        for (int ct = 0; ct < 3; ++ct)
            acc[ct] = __builtin_amdgcn_mfma_f32_16x16x32_bf16(
                a, bfrag[ct][kt], acc[ct], 0, 0, 0);
    }
    #pragma unroll
    for (int reg = 0; reg < 4; ++reg) {
        float v0 = acc[0][reg], v1 = acc[1][reg];
        float v2 = (lr < 8) ? acc[2][reg] : -INFINITY;
        float mx = fmaxf(fmaxf(v0, v1), v2);
        mx = fmaxf(mx, __shfl_xor(mx, 1, 64));
        mx = fmaxf(mx, __shfl_xor(mx, 2, 64));
        mx = fmaxf(mx, __shfl_xor(mx, 4, 64));
        mx = fmaxf(mx, __shfl_xor(mx, 8, 64));
        float e = expf(v0 - mx) + expf(v1 - mx) + ((lr < 8) ? expf(v2 - mx) : 0.f);
        e += __shfl_xor(e, 1, 64);
        e += __shfl_xor(e, 2, 64);
        e += __shfl_xor(e, 4, 64);
        e += __shfl_xor(e, 8, 64);
        float ls = mx + logf(e);
        int n = nbase + lg * 4 + reg;
        if (n < N_NODES) {
            out[(size_t)n * C_OUT + lr]      = v0 - ls;
            out[(size_t)n * C_OUT + 16 + lr] = v1 - ls;
            if (lr < 8) out[(size_t)n * C_OUT + 32 + lr] = v2 - ls;
        }
    }
}

__global__ __launch_bounds__(256) void k_entreduce(
    const float* __restrict__ part, int n, float scale, float* __restrict__ out)
{
    __shared__ float lds[4];
    int tid = threadIdx.x;
    float s = 0.f;
    for (int i = tid; i < n; i += 256) s += part[i];
    s = waveReduceSum(s);
    int wave = tid >> 6, lane = tid & 63;
    if (lane == 0) lds[wave] = s;
    __syncthreads();
    if (tid == 0) out[0] = (lds[0] + lds[1] + lds[2] + lds[3]) * scale;
}

extern "C" void kernel_launch(void* const* d_in, const int* in_sizes, int n_in,
                              void* d_out, int out_size, void* d_ws, size_t ws_size,
                              hipStream_t stream)
{
    const float* x   = (const float*)d_in[0];
    const float* ew  = (const float*)d_in[1];
    const float* gum = (const float*)d_in[2];
    const float* W0  = (const float*)d_in[3];
    const float* b0  = (const float*)d_in[4];
    const float* mw  = (const float*)d_in[5];
    const float* mb  = (const float*)d_in[6];
    const float* W1  = (const float*)d_in[7];
    const float* b1  = (const float*)d_in[8];
    const int* esrc  = (const int*)d_in[9];
    const int* edst  = (const int*)d_in[10];
    float* out = (float*)d_out;

    const int propBlocks = (N_NODES + 31) / 32;         // 5313

    const size_t xMatBytes = (size_t)N_NODES * ROW_ELEMS * sizeof(u16); // 195,840,000
    const size_t degBytes  = (size_t)N_NODES * sizeof(int);
    const size_t curBytes  = (size_t)N_NODES * sizeof(int);
    const size_t rowBytes  = (size_t)N_NODES * sizeof(int);
    const size_t bsBytes   = 512;
    const size_t csrBytes  = (size_t)N_EDGES * sizeof(int2);            //  19,200,000
    const size_t mixBytes  = (size_t)N_NODES * H_ * sizeof(u16);        //  21,760,000
    const size_t entBytes  = (size_t)propBlocks * sizeof(float);        //      21,252
    const size_t need = xMatBytes + degBytes + curBytes + rowBytes + bsBytes +
                        csrBytes + mixBytes + entBytes;                 // ~238.9 MB
    if (ws_size < need) return;

    char* p = (char*)d_ws;
    u16*  xMatB    = (u16*)p;           p += xMatBytes;
    int*  deg      = (int*)p;           p += degBytes;
    int*  cursor   = (int*)p;           p += curBytes;   // deg+cursor zeroed together
    int*  rowstart = (int*)p;           p += rowBytes;
    int*  blockSums= (int*)p;           p += bsBytes;
    int2* csr      = (int2*)p;          p += csrBytes;
    u16*  mixbuf   = (u16*)p;           p += mixBytes;
    float* entP    = (float*)p;

    const int edgeBlocks = (N_EDGES + 255) / 256;       // 9375
    const int lin0Blocks = (N_NODES + 255) / 256;       // 665
    const int gmixBlocks = propBlocks;                  // 5313
    const int lin1Blocks = (N_NODES + 63) / 64;         // 2657

    // CSR build (k_zero4 zeroes deg+cursor; 3968B tail spills into rowstart,
    // which scan rewrites fully before any read)
    k_zero4<<<333, 256, 0, stream>>>((float4*)deg);
    const int STEP_H = N_NODES / 2;                     // 85000: 340KB deg window
    for (int i = 0; i < 2; ++i)
        k_hist<<<edgeBlocks, 256, 0, stream>>>(edst, deg, i * STEP_H,
                                               (i + 1) * STEP_H);
    k_scan1<<<SCAN_BLOCKS, SCAN_TPB, 0, stream>>>(deg, rowstart, blockSums);
    k_scan2<<<1, 64, 0, stream>>>(blockSums);
    k_scan3<<<SCAN_BLOCKS, SCAN_TPB, 0, stream>>>(rowstart, blockSums);
    const int STEP_B = N_NODES / 8;                     // 21250: 2.4MB csr window
    for (int i = 0; i < 8; ++i)
        k_bucket<<<edgeBlocks, 256, 0, stream>>>(esrc, edst, ew, rowstart,
                                                 cursor, csr, i * STEP_B,
                                                 (i + 1) * STEP_B);

    // node pipeline
    k_lin0<<<lin0Blocks, 256, 0, stream>>>(x, W0, b0, xMatB);
    for (int l = 0; l < L_LAYERS; ++l)
        k_prop<<<propBlocks, 256, 0, stream>>>(xMatB, l, rowstart, deg, csr,
                                               xMatB);
    k_gatemix<<<gmixBlocks, 256, 0, stream>>>(xMatB, gum, mw, mb, mixbuf, entP);
    k_lin1<<<lin1Blocks, 256, 0, stream>>>(mixbuf, W1, b1, out);
    k_entreduce<<<1, 256, 0, stream>>>(entP, gmixBlocks, 1.0f / N_NODES,
                                       out + (size_t)N_NODES * C_OUT);
}